// Round 12
// baseline (3149979.883 us; speedup 1.0000x reference)
//
#include <hip/hip_runtime.h>
#include <math.h>

#define B_  512
#define T_  256
#define I_  64
#define H_  512
#define G4  2048
#define K_  576   // 512 (h) + 64 (x)
#define HN  30
#define EPSf 1e-5f
#define GW  16    // blocks per group (j-blocks)
#define NG  16    // groups (m-blocks)
#define BM  32
#define BJ  32
#define KP  520   // As pitch in shorts (512 + 8 pad)
#define A1P 32    // a1p padded feature stride
#define HROT 4    // h buffer rotation (skew<=1 + margin)

typedef __attribute__((ext_vector_type(8))) short short8;
typedef __attribute__((ext_vector_type(4))) float f32x4;

static __device__ __forceinline__ unsigned short f2bf(float f) {
    unsigned int u = __float_as_uint(f);
    u += 0x7fffu + ((u >> 16) & 1u);   // round-to-nearest-even
    return (unsigned short)(u >> 16);
}
static __device__ __forceinline__ float sigf(float x) {
    return __builtin_amdgcn_rcpf(1.0f + __expf(-x));
}
static __device__ __forceinline__ float tanh_f(float x) {
    float e = __expf(-2.0f * fabsf(x));
    float r = (1.0f - e) * __builtin_amdgcn_rcpf(1.0f + e);
    return copysignf(r, x);
}

// ---------------------------------------------------------------- pack / init
__global__ void pack_kernel(const float* __restrict__ x, const float* __restrict__ Wih,
                            const float* __restrict__ Whh, const float* __restrict__ bih,
                            const float* __restrict__ bhh, const float* __restrict__ l1w,
                            unsigned short* __restrict__ Wp, unsigned short* __restrict__ xb,
                            float* __restrict__ bias, unsigned short* __restrict__ hb,
                            float* __restrict__ a1p, unsigned short* __restrict__ wl1b,
                            unsigned int* __restrict__ arr, unsigned int* __restrict__ map) {
    const int stride = gridDim.x * blockDim.x;
    const int g0 = blockIdx.x * blockDim.x + threadIdx.x;
    for (int idx = g0; idx < G4 * K_; idx += stride) {
        int n = idx / K_, k = idx - n * K_;
        float v = (k < H_) ? Whh[n * H_ + k] : Wih[n * I_ + (k - H_)];
        Wp[idx] = f2bf(v);
    }
    for (int idx = g0; idx < T_ * B_ * I_; idx += stride) {
        int t = idx / (B_ * I_);
        int r = idx - t * (B_ * I_);
        int b = r / I_, i = r - b * I_;
        xb[idx] = f2bf(x[((size_t)b * T_ + t) * I_ + i]);
    }
    for (int idx = g0; idx < G4; idx += stride) bias[idx] = bih[idx] + bhh[idx];
    for (int idx = g0; idx < B_ * H_; idx += stride) hb[idx] = 0;  // slot 0: h(-1)=0
    for (int idx = g0; idx < T_ * B_ * A1P; idx += stride) a1p[idx] = 0.0f;
    for (int idx = g0; idx < 32 * H_; idx += stride) {
        int f = idx >> 9, k = idx & 511;
        wl1b[idx] = (f < HN) ? f2bf(l1w[f * H_ + k]) : 0;
    }
    for (int idx = g0; idx < NG * 64; idx += stride) arr[idx] = 0u;
    for (int idx = g0; idx < 256; idx += stride) map[idx] = 0u;
}

// ---------------------------------------------------------------- persistent LSTM
// 256 blocks (1/CU) x 256 threads. bid = jb*16 + mb. Group = 16 blocks, same mb.
// R12 critical-path cuts on the R11 structure (coherence mechanisms unchanged,
// all R10/R11-proven): (1) per-wave sc0-LOAD polls -- no tid0 funnel, no
// post-poll barrier/wake; (2) per-wave release via monotonic LDS ds_add, 4th
// wave issues the global signal -- no post-store barrier; (3) x operand kept in
// registers (2 tail MFMAs), As = [32][520]; (4) l1 partial issued before the
// release drain so its atomics share the store's L2 ack round trip.
__global__ __launch_bounds__(256, 1) void lstm_kernel(
        const unsigned short* __restrict__ Wp, const unsigned short* __restrict__ xb,
        const float* __restrict__ bias, unsigned short* __restrict__ hb,
        float* __restrict__ a1p, const unsigned short* __restrict__ wl1b,
        unsigned int* __restrict__ arr, unsigned int* __restrict__ map) {
    __shared__ unsigned short As[BM][KP];     // A-tile: h only (512), padded
    __shared__ unsigned short hsb[BM][40];    // new h (bf16): store + l1 source
    __shared__ int flagLDS;
    __shared__ unsigned wsig;                 // monotonic per-block wave-arrival ctr

    const int tid  = threadIdx.x;
    const int w    = tid >> 6;         // wave = quadrant
    const int lane = tid & 63;
    const int r    = lane & 15;        // MFMA: A-row / B-col / D-col
    const int q    = lane >> 4;        // MFMA: k-chunk / D-row group
    const int mt   = w >> 1;           // row half (0..1)
    const int jt   = w & 1;            // col half (0..1)
    const int mb   = blockIdx.x & 15;
    const int jb   = blockIdx.x >> 4;
    const int m0   = mb * BM;
    const int j0   = jb * BJ;
    const int hrow = tid >> 3, hseg = tid & 7;   // staging: lanes 0..7 share hrow
    const int mt_l1 = w >> 1, ft_l1 = w & 1;     // l1 tile per wave

    if (tid == 0) {
        unsigned xcc;
        asm volatile("s_getreg_b32 %0, hwreg(HW_REG_XCC_ID)" : "=s"(xcc));
        __hip_atomic_store(&map[blockIdx.x], 0x100u | (xcc & 0xffu),
                           __ATOMIC_RELAXED, __HIP_MEMORY_SCOPE_AGENT);
        wsig = 0u;
    }

    // ---- persistent W fragments: 4 gates x 18 k-chunks for cols j0+jt*16+r
    short8 bfrag[4][18];
#pragma unroll
    for (int g = 0; g < 4; ++g)
#pragma unroll
        for (int kc = 0; kc < 18; ++kc) {
            bfrag[g][kc] = *reinterpret_cast<const short8*>(
                Wp + (size_t)(g * H_ + j0 + jt * 16 + r) * K_ + kc * 32 + q * 8);
            asm volatile("" : "+v"(bfrag[g][kc]));
        }
    short8 bl1 = *reinterpret_cast<const short8*>(
        wl1b + (size_t)(ft_l1 * 16 + r) * H_ + j0 + q * 8);
    asm volatile("" : "+v"(bl1));

    float bias_g[4];
#pragma unroll
    for (int g = 0; g < 4; ++g) bias_g[g] = bias[g * H_ + j0 + jt * 16 + r];

    float c[4] = {0.f, 0.f, 0.f, 0.f};
    unsigned int* ctrA = arr + mb * 64;        // agent-scope counter (IF$ path)
    unsigned int* ctrB = arr + mb * 64 + 32;   // L2-point counter (fast path)
    int fastf = 0;

#pragma unroll 1
    for (int t = 0; t < T_; ++t) {
        const unsigned short* hin = hb + (size_t)(t % HROT) * B_ * H_;
        unsigned short* hout      = hb + (size_t)((t + 1) % HROT) * B_ * H_;

        // ---- wait for h(t-1)
        if (t > 0) {
            if (fastf) {
                // per-wave sc0-load poll (L1-bypass proven R10); no barrier
                const unsigned target = (unsigned)(GW * (t - 1));
                unsigned tries = 0;
                for (;;) {
                    unsigned v;
                    asm volatile("global_load_dword %0, %1, off sc0\n\t"
                                 "s_waitcnt vmcnt(0)"
                                 : "=v"(v) : "v"(ctrB) : "memory");
                    if (v >= target) break;
                    if (++tries > 100000u) break;   // fail loud, never wedge
                    __builtin_amdgcn_s_sleep(1);
                }
            } else {
                if (tid == 0) {
                    const unsigned target = (unsigned)(GW * t);
                    unsigned tries = 0;
                    while (__hip_atomic_load(ctrA, __ATOMIC_RELAXED,
                                             __HIP_MEMORY_SCOPE_AGENT) < target) {
                        if (++tries > 100000u) break;
                        __builtin_amdgcn_s_sleep(1);
                    }
                    if (t == 1) {   // group XCD homogeneity check (once)
                        unsigned v0 = __hip_atomic_load(&map[mb], __ATOMIC_RELAXED,
                                                        __HIP_MEMORY_SCOPE_AGENT);
                        int same = (v0 & 0x100u) ? 1 : 0;
                        for (int u = 1; u < GW; ++u) {
                            unsigned vu = __hip_atomic_load(&map[u * 16 + mb],
                                                            __ATOMIC_RELAXED,
                                                            __HIP_MEMORY_SCOPE_AGENT);
                            same &= (vu == v0);
                        }
                        flagLDS = same;
                    }
                }
                __syncthreads();
                if (t == 1) fastf = flagLDS;
                asm volatile("" ::: "memory");
            }
        }

        // ---- x fragments for this wave's rows: direct global->reg (post-poll)
        const unsigned short* xr = xb + ((size_t)t * B_ + m0 + mt * 16 + r) * I_ + q * 8;
        const short8 xf0 = *reinterpret_cast<const short8*>(xr);
        const short8 xf1 = *reinterpret_cast<const short8*>(xr + 32);

        // ---- stage A-tile (h only): chunk u at col u*64+hseg*8, lane-contiguous
        short8 hv[8];
        const unsigned short* hbase = hin + (size_t)(m0 + hrow) * H_ + hseg * 8;
        if (fastf) {
#pragma unroll
            for (int u = 0; u < 8; ++u)
                asm volatile("global_load_dwordx4 %0, %1, off sc0"
                             : "=&v"(hv[u]) : "v"(hbase + u * 64));
        } else {
#pragma unroll
            for (int u = 0; u < 8; ++u) {
                unsigned long long p2[2];
                p2[0] = __hip_atomic_load((const unsigned long long*)(hbase + u * 64),
                                          __ATOMIC_RELAXED, __HIP_MEMORY_SCOPE_AGENT);
                p2[1] = __hip_atomic_load((const unsigned long long*)(hbase + u * 64 + 4),
                                          __ATOMIC_RELAXED, __HIP_MEMORY_SCOPE_AGENT);
                __builtin_memcpy(&hv[u], p2, 16);
            }
        }
        asm volatile("s_waitcnt vmcnt(0)" ::: "memory");
        __builtin_amdgcn_sched_barrier(0);
#pragma unroll
        for (int u = 0; u < 8; ++u)
            *reinterpret_cast<short8*>(&As[hrow][u * 64 + hseg * 8]) = hv[u];
        __syncthreads();   // stage barrier (also orders prev-step tails)

        // ---- GEMM: 16 h k-chunks from LDS + 2 x k-chunks from registers
        f32x4 acc[4];
#pragma unroll
        for (int g = 0; g < 4; ++g)
            acc[g] = (f32x4){bias_g[g], bias_g[g], bias_g[g], bias_g[g]};
#pragma unroll
        for (int kc = 0; kc < 16; ++kc) {
            const short8 afr = *reinterpret_cast<const short8*>(
                &As[mt * 16 + r][kc * 32 + q * 8]);
#pragma unroll
            for (int g = 0; g < 4; ++g)
                acc[g] = __builtin_amdgcn_mfma_f32_16x16x32_bf16(
                    afr, bfrag[g][kc], acc[g], 0, 0, 0);
        }
#pragma unroll
        for (int g = 0; g < 4; ++g) {
            acc[g] = __builtin_amdgcn_mfma_f32_16x16x32_bf16(xf0, bfrag[g][16], acc[g], 0, 0, 0);
            acc[g] = __builtin_amdgcn_mfma_f32_16x16x32_bf16(xf1, bfrag[g][17], acc[g], 0, 0, 0);
        }

        // ---- cell update: lane-local (D col=r, row=q*4+rr); c in regs
#pragma unroll
        for (int rr = 0; rr < 4; ++rr) {
            float ig = acc[0][rr], fg = acc[1][rr], gg = acc[2][rr], og = acc[3][rr];
            float cn = sigf(fg) * c[rr] + sigf(ig) * tanh_f(gg);
            c[rr] = cn;
            hsb[mt * 16 + q * 4 + rr][jt * 16 + r] = f2bf(sigf(og) * tanh_f(cn));
        }
        __syncthreads();   // hsb complete

        // ---- h store (8B/thread) + l1 partial, then ONE drain for both
        {
            unsigned long long pv;
            __builtin_memcpy(&pv, &hsb[hrow][hseg * 4], 8);
            unsigned long long* hdst = (unsigned long long*)(hout
                + (size_t)(m0 + hrow) * H_ + j0 + hseg * 4);
            if (fastf) *hdst = pv;   // plain store: write-through L1 -> shared L2
            else __hip_atomic_store(hdst, pv, __ATOMIC_RELAXED,
                                    __HIP_MEMORY_SCOPE_AGENT);
        }
        {
            const short8 ah = *reinterpret_cast<const short8*>(&hsb[mt_l1 * 16 + r][q * 8]);
            f32x4 d = __builtin_amdgcn_mfma_f32_16x16x32_bf16(
                ah, bl1, (f32x4){0.f, 0.f, 0.f, 0.f}, 0, 0, 0);
            const int f = ft_l1 * 16 + r;
            if (f < HN) {
                float* dst = a1p + ((size_t)t * B_ + m0 + mt_l1 * 16 + q * 4) * A1P + f;
                if (fastf) {
#pragma unroll
                    for (int rr = 0; rr < 4; ++rr) {
                        float* p = dst + rr * A1P;
                        asm volatile("global_atomic_add_f32 %0, %1, off"
                                     :: "v"(p), "v"(d[rr]) : "memory");
                    }
                } else {
#pragma unroll
                    for (int rr = 0; rr < 4; ++rr)
                        __hip_atomic_fetch_add(dst + rr * A1P, d[rr], __ATOMIC_RELAXED,
                                               __HIP_MEMORY_SCOPE_AGENT);
                }
            }
        }
        // drain: h store + l1 atomics acked at L2/IF$ in one round trip
        asm volatile("s_waitcnt vmcnt(0)" ::: "memory");

        // ---- per-wave release: monotonic LDS arrival; 4th wave signals group
        if (t + 1 < T_) {
            if (lane == 0) {
                unsigned old = atomicAdd(&wsig, 1u);
                if (old == (unsigned)(4 * (t + 1) - 1)) {
                    if (fastf) {
                        unsigned one = 1;
                        asm volatile("global_atomic_add %0, %1, off"
                                     :: "v"(ctrB), "v"(one) : "memory");
                    } else {
                        __hip_atomic_fetch_add(ctrA, 1u, __ATOMIC_RELAXED,
                                               __HIP_MEMORY_SCOPE_AGENT);
                    }
                }
            }
            if (!fastf) __syncthreads();   // fallback keeps strict step lockstep
        }
    }
}

// ---------------------------------------------------------------- MLP head
static __device__ __forceinline__ void bn_relu30(float v[HN], const float* __restrict__ gamma,
                                                 const float* __restrict__ beta,
                                                 float (*pS)[HN], float (*pQ)[HN]) {
    float s0[HN], s1[HN];
#pragma unroll
    for (int f = 0; f < HN; ++f) { s0[f] = v[f]; s1[f] = v[f] * v[f]; }
#pragma unroll
    for (int off = 32; off >= 1; off >>= 1) {
#pragma unroll
        for (int f = 0; f < HN; ++f) {
            s0[f] += __shfl_xor(s0[f], off);
            s1[f] += __shfl_xor(s1[f], off);
        }
    }
    const int lane = threadIdx.x & 63, w = threadIdx.x >> 6;
    if (lane == 0) {
#pragma unroll
        for (int f = 0; f < HN; ++f) { pS[w][f] = s0[f]; pQ[w][f] = s1[f]; }
    }
    __syncthreads();
#pragma unroll
    for (int f = 0; f < HN; ++f) {
        float S = 0.f, Q = 0.f;
#pragma unroll
        for (int u = 0; u < 8; ++u) { S += pS[u][f]; Q += pQ[u][f]; }
        float m = S * (1.0f / 512.0f);
        float var = Q * (1.0f / 512.0f) - m * m;     // biased, matches jnp.mean
        float inv = 1.0f / sqrtf(var + EPSf);
        float tv = gamma[f] * (v[f] - m) * inv + beta[f];
        v[f] = fmaxf(tv, 0.f);
    }
    __syncthreads();
}

static __device__ __forceinline__ void layer30(float v[HN], const float* __restrict__ w) {
    float u[HN];
#pragma unroll
    for (int f = 0; f < HN; ++f) {
        float a = 0.f;
#pragma unroll
        for (int k = 0; k < HN; ++k) a = fmaf(v[k], w[f * HN + k], a);
        u[f] = a;
    }
#pragma unroll
    for (int f = 0; f < HN; ++f) v[f] = u[f];
}

__global__ __launch_bounds__(512) void mlp_kernel(
        const float* __restrict__ a1p, const float* __restrict__ l1b,
        const float* __restrict__ l2w, const float* __restrict__ l3w,
        const float* __restrict__ l4w, const float* __restrict__ l5w,
        const float* __restrict__ gamma, const float* __restrict__ beta,
        float* __restrict__ out) {
    const int t = blockIdx.x;
    const int b = threadIdx.x;
    __shared__ float pS[8][HN], pQ[8][HN];
    float v[HN];
    const float* src = a1p + ((size_t)t * B_ + b) * A1P;
#pragma unroll
    for (int f = 0; f < HN; ++f) v[f] = src[f] + l1b[f];
    bn_relu30(v, gamma, beta, pS, pQ);
    layer30(v, l2w); bn_relu30(v, gamma, beta, pS, pQ);
    layer30(v, l3w); bn_relu30(v, gamma, beta, pS, pQ);
    layer30(v, l4w); bn_relu30(v, gamma, beta, pS, pQ);
    float o0 = 0.f, o1 = 0.f;
#pragma unroll
    for (int k = 0; k < HN; ++k) {
        o0 = fmaf(v[k], l5w[k], o0);
        o1 = fmaf(v[k], l5w[HN + k], o1);
    }
    out[(size_t)b * (2 * T_) + t]      = o0;   // out[b][0][t]
    out[(size_t)b * (2 * T_) + T_ + t] = o1;   // out[b][1][t]
}

// ---------------------------------------------------------------- launch
extern "C" void kernel_launch(void* const* d_in, const int* in_sizes, int n_in,
                              void* d_out, int out_size, void* d_ws, size_t ws_size,
                              hipStream_t stream) {
    const float* x    = (const float*)d_in[0];
    const float* Wih  = (const float*)d_in[1];
    const float* Whh  = (const float*)d_in[2];
    const float* bih  = (const float*)d_in[3];
    const float* bhh  = (const float*)d_in[4];
    const float* l1w  = (const float*)d_in[5];
    const float* l1b  = (const float*)d_in[6];
    const float* l2w  = (const float*)d_in[7];
    const float* l3w  = (const float*)d_in[8];
    const float* l4w  = (const float*)d_in[9];
    const float* l5w  = (const float*)d_in[10];
    const float* gam  = (const float*)d_in[11];
    const float* bet  = (const float*)d_in[12];
    float* out = (float*)d_out;

    char* ws = (char*)d_ws;
    unsigned short* Wp   = (unsigned short*)ws;  ws += (size_t)G4 * K_ * 2;            // 2.36 MB
    unsigned short* xb   = (unsigned short*)ws;  ws += (size_t)T_ * B_ * I_ * 2;       // 16.8 MB
    float*          bia  = (float*)ws;           ws += (size_t)G4 * 4;                 // 8 KB
    unsigned short* hb   = (unsigned short*)ws;  ws += (size_t)HROT * B_ * H_ * 2;     // 2 MB
    float*          a1p  = (float*)ws;           ws += (size_t)T_ * B_ * A1P * 4;      // 16.8 MB
    unsigned short* wl1b = (unsigned short*)ws;  ws += (size_t)32 * H_ * 2;            // 32 KB
    unsigned int*   arr  = (unsigned int*)ws;    ws += (size_t)NG * 64 * 4;            // 4 KB
    unsigned int*   map  = (unsigned int*)ws;    ws += (size_t)256 * 4;                // 1 KB

    pack_kernel<<<1024, 256, 0, stream>>>(x, Wih, Whh, bih, bhh, l1w,
                                          Wp, xb, bia, hb, a1p, wl1b, arr, map);
    lstm_kernel<<<NG * GW, 256, 0, stream>>>(Wp, xb, bia, hb, a1p, wl1b, arr, map);
    mlp_kernel<<<T_, 512, 0, stream>>>(a1p, l1b, l2w, l3w, l4w, l5w, gam, bet, out);
}

// Round 13
// 1439.299 us; speedup vs baseline: 2188.5513x; 2188.5513x over previous
//
#include <hip/hip_runtime.h>
#include <math.h>

#define B_  512
#define T_  256
#define I_  64
#define H_  512
#define G4  2048
#define K_  576   // 512 (h) + 64 (x)
#define HN  30
#define EPSf 1e-5f
#define GW  16    // blocks per group (j-blocks)
#define NG  16    // groups (m-blocks)
#define BM  32
#define BJ  32
#define KP  520   // As pitch in shorts (512 + 8 pad)
#define A1P 32    // a1p padded feature stride
#define HROT 4    // h buffer rotation (L1 eviction + WAR margin)

typedef __attribute__((ext_vector_type(8))) short short8;
typedef __attribute__((ext_vector_type(4))) float f32x4;

static __device__ __forceinline__ unsigned short f2bf(float f) {
    unsigned int u = __float_as_uint(f);
    u += 0x7fffu + ((u >> 16) & 1u);   // round-to-nearest-even
    return (unsigned short)(u >> 16);
}
static __device__ __forceinline__ float sigf(float x) {
    return __builtin_amdgcn_rcpf(1.0f + __expf(-x));
}
static __device__ __forceinline__ float tanh_f(float x) {
    float e = __expf(-2.0f * fabsf(x));
    float r = (1.0f - e) * __builtin_amdgcn_rcpf(1.0f + e);
    return copysignf(r, x);
}

// ---------------------------------------------------------------- pack / init
__global__ void pack_kernel(const float* __restrict__ x, const float* __restrict__ Wih,
                            const float* __restrict__ Whh, const float* __restrict__ bih,
                            const float* __restrict__ bhh, const float* __restrict__ l1w,
                            unsigned short* __restrict__ Wp, unsigned short* __restrict__ xb,
                            float* __restrict__ bias, unsigned short* __restrict__ hb,
                            float* __restrict__ a1p, unsigned short* __restrict__ wl1b,
                            unsigned int* __restrict__ arr, unsigned int* __restrict__ map) {
    const int stride = gridDim.x * blockDim.x;
    const int g0 = blockIdx.x * blockDim.x + threadIdx.x;
    for (int idx = g0; idx < G4 * K_; idx += stride) {
        int n = idx / K_, k = idx - n * K_;
        float v = (k < H_) ? Whh[n * H_ + k] : Wih[n * I_ + (k - H_)];
        Wp[idx] = f2bf(v);
    }
    for (int idx = g0; idx < T_ * B_ * I_; idx += stride) {
        int t = idx / (B_ * I_);
        int r = idx - t * (B_ * I_);
        int b = r / I_, i = r - b * I_;
        xb[idx] = f2bf(x[((size_t)b * T_ + t) * I_ + i]);
    }
    for (int idx = g0; idx < G4; idx += stride) bias[idx] = bih[idx] + bhh[idx];
    for (int idx = g0; idx < B_ * H_; idx += stride) hb[idx] = 0;  // slot 0: h(-1)=0
    for (int idx = g0; idx < T_ * B_ * A1P; idx += stride) a1p[idx] = 0.0f;
    for (int idx = g0; idx < 32 * H_; idx += stride) {
        int f = idx >> 9, k = idx & 511;
        wl1b[idx] = (f < HN) ? f2bf(l1w[f * H_ + k]) : 0;
    }
    for (int idx = g0; idx < NG * 64; idx += stride) arr[idx] = 0u;
    for (int idx = g0; idx < 256; idx += stride) map[idx] = 0u;
}

// ---------------------------------------------------------------- persistent LSTM
// 256 blocks (1/CU) x 256 threads. bid = jb*16 + mb. Group = 16 blocks, same mb.
// HW facts accumulated: (F1) atomic RMWs execute at the L2 point and are the
// ONLY L1-immune read (R10/R11 worked; R6/R12 sc0-load polls timed out);
// (F2) sc0/plain h loads are fresh because HROT rotation guarantees L1
// eviction between re-reads; (F3) pinned W fragments land in unified-file
// AGPRs and stay resident (R8). R13 = R12's critical-path cuts with the poll
// reverted to the per-wave lane0 RMW: no tid0 funnel, no post-poll barrier,
// no post-store barrier, x in regs, merged store+l1 drain.
__global__ __launch_bounds__(256, 1) void lstm_kernel(
        const unsigned short* __restrict__ Wp, const unsigned short* __restrict__ xb,
        const float* __restrict__ bias, unsigned short* __restrict__ hb,
        float* __restrict__ a1p, const unsigned short* __restrict__ wl1b,
        unsigned int* __restrict__ arr, unsigned int* __restrict__ map) {
    __shared__ unsigned short As[BM][KP];     // A-tile: h only (512), padded
    __shared__ unsigned short hsb[BM][40];    // new h (bf16): store + l1 source
    __shared__ int flagLDS;
    __shared__ unsigned wsig;                 // monotonic per-block wave-arrival ctr

    const int tid  = threadIdx.x;
    const int w    = tid >> 6;         // wave = quadrant
    const int lane = tid & 63;
    const int r    = lane & 15;        // MFMA: A-row / B-col / D-col
    const int q    = lane >> 4;        // MFMA: k-chunk / D-row group
    const int mt   = w >> 1;           // row half (0..1)
    const int jt   = w & 1;            // col half (0..1)
    const int mb   = blockIdx.x & 15;
    const int jb   = blockIdx.x >> 4;
    const int m0   = mb * BM;
    const int j0   = jb * BJ;
    const int hrow = tid >> 3, hseg = tid & 7;   // staging: lanes 0..7 share hrow
    const int mt_l1 = w >> 1, ft_l1 = w & 1;     // l1 tile per wave

    if (tid == 0) {
        unsigned xcc;
        asm volatile("s_getreg_b32 %0, hwreg(HW_REG_XCC_ID)" : "=s"(xcc));
        __hip_atomic_store(&map[blockIdx.x], 0x100u | (xcc & 0xffu),
                           __ATOMIC_RELAXED, __HIP_MEMORY_SCOPE_AGENT);
        wsig = 0u;
    }

    // ---- persistent W fragments: 4 gates x 18 k-chunks for cols j0+jt*16+r
    short8 bfrag[4][18];
#pragma unroll
    for (int g = 0; g < 4; ++g)
#pragma unroll
        for (int kc = 0; kc < 18; ++kc) {
            bfrag[g][kc] = *reinterpret_cast<const short8*>(
                Wp + (size_t)(g * H_ + j0 + jt * 16 + r) * K_ + kc * 32 + q * 8);
            asm volatile("" : "+v"(bfrag[g][kc]));
        }
    short8 bl1 = *reinterpret_cast<const short8*>(
        wl1b + (size_t)(ft_l1 * 16 + r) * H_ + j0 + q * 8);
    asm volatile("" : "+v"(bl1));

    float bias_g[4];
#pragma unroll
    for (int g = 0; g < 4; ++g) bias_g[g] = bias[g * H_ + j0 + jt * 16 + r];

    float c[4] = {0.f, 0.f, 0.f, 0.f};
    unsigned int* ctrA = arr + mb * 64;        // agent-scope counter (IF$ path)
    unsigned int* ctrB = arr + mb * 64 + 32;   // L2-point counter (fast path)
    int fastf = 0;

#pragma unroll 1
    for (int t = 0; t < T_; ++t) {
        const unsigned short* hin = hb + (size_t)(t % HROT) * B_ * H_;
        unsigned short* hout      = hb + (size_t)((t + 1) % HROT) * B_ * H_;

        // ---- wait for h(t-1)
        if (t > 0) {
            if (fastf) {
                // per-wave lane0 RMW poll (F1): whole wave waits via exec mask
                if (lane == 0) {
                    const unsigned target = (unsigned)(GW * (t - 1));
                    unsigned tries = 0;
                    for (;;) {
                        unsigned old, zero = 0;
                        asm volatile("global_atomic_add %0, %1, %2, off sc0\n\t"
                                     "s_waitcnt vmcnt(0)"
                                     : "=&v"(old) : "v"(ctrB), "v"(zero) : "memory");
                        if (old >= target) break;
                        if (++tries > 100000u) break;   // fail loud, never wedge
                        __builtin_amdgcn_s_sleep(1);
                    }
                }
            } else {
                if (tid == 0) {
                    const unsigned target = (unsigned)(GW * t);
                    unsigned tries = 0;
                    while (__hip_atomic_load(ctrA, __ATOMIC_RELAXED,
                                             __HIP_MEMORY_SCOPE_AGENT) < target) {
                        if (++tries > 100000u) break;
                        __builtin_amdgcn_s_sleep(1);
                    }
                    if (t == 1) {   // group XCD homogeneity check (once)
                        unsigned v0 = __hip_atomic_load(&map[mb], __ATOMIC_RELAXED,
                                                        __HIP_MEMORY_SCOPE_AGENT);
                        int same = (v0 & 0x100u) ? 1 : 0;
                        for (int u = 1; u < GW; ++u) {
                            unsigned vu = __hip_atomic_load(&map[u * 16 + mb],
                                                            __ATOMIC_RELAXED,
                                                            __HIP_MEMORY_SCOPE_AGENT);
                            same &= (vu == v0);
                        }
                        flagLDS = same;
                    }
                }
                __syncthreads();
                if (t == 1) fastf = flagLDS;
                asm volatile("" ::: "memory");
            }
        }

        // ---- x fragments for this wave's rows: direct global->reg (post-poll)
        const unsigned short* xr = xb + ((size_t)t * B_ + m0 + mt * 16 + r) * I_ + q * 8;
        const short8 xf0 = *reinterpret_cast<const short8*>(xr);
        const short8 xf1 = *reinterpret_cast<const short8*>(xr + 32);

        // ---- stage A-tile (h only): chunk u at col u*64+hseg*8, lane-contiguous
        short8 hv[8];
        const unsigned short* hbase = hin + (size_t)(m0 + hrow) * H_ + hseg * 8;
        if (fastf) {
#pragma unroll
            for (int u = 0; u < 8; ++u)
                asm volatile("global_load_dwordx4 %0, %1, off sc0"
                             : "=&v"(hv[u]) : "v"(hbase + u * 64));
        } else {
#pragma unroll
            for (int u = 0; u < 8; ++u) {
                unsigned long long p2[2];
                p2[0] = __hip_atomic_load((const unsigned long long*)(hbase + u * 64),
                                          __ATOMIC_RELAXED, __HIP_MEMORY_SCOPE_AGENT);
                p2[1] = __hip_atomic_load((const unsigned long long*)(hbase + u * 64 + 4),
                                          __ATOMIC_RELAXED, __HIP_MEMORY_SCOPE_AGENT);
                __builtin_memcpy(&hv[u], p2, 16);
            }
        }
        asm volatile("s_waitcnt vmcnt(0)" ::: "memory");
        __builtin_amdgcn_sched_barrier(0);
#pragma unroll
        for (int u = 0; u < 8; ++u)
            *reinterpret_cast<short8*>(&As[hrow][u * 64 + hseg * 8]) = hv[u];
        __syncthreads();   // stage barrier (also orders prev-step tails)

        // ---- GEMM: 16 h k-chunks from LDS + 2 x k-chunks from registers
        f32x4 acc[4];
#pragma unroll
        for (int g = 0; g < 4; ++g)
            acc[g] = (f32x4){bias_g[g], bias_g[g], bias_g[g], bias_g[g]};
#pragma unroll
        for (int kc = 0; kc < 16; ++kc) {
            const short8 afr = *reinterpret_cast<const short8*>(
                &As[mt * 16 + r][kc * 32 + q * 8]);
#pragma unroll
            for (int g = 0; g < 4; ++g)
                acc[g] = __builtin_amdgcn_mfma_f32_16x16x32_bf16(
                    afr, bfrag[g][kc], acc[g], 0, 0, 0);
        }
#pragma unroll
        for (int g = 0; g < 4; ++g) {
            acc[g] = __builtin_amdgcn_mfma_f32_16x16x32_bf16(xf0, bfrag[g][16], acc[g], 0, 0, 0);
            acc[g] = __builtin_amdgcn_mfma_f32_16x16x32_bf16(xf1, bfrag[g][17], acc[g], 0, 0, 0);
        }

        // ---- cell update: lane-local (D col=r, row=q*4+rr); c in regs
#pragma unroll
        for (int rr = 0; rr < 4; ++rr) {
            float ig = acc[0][rr], fg = acc[1][rr], gg = acc[2][rr], og = acc[3][rr];
            float cn = sigf(fg) * c[rr] + sigf(ig) * tanh_f(gg);
            c[rr] = cn;
            hsb[mt * 16 + q * 4 + rr][jt * 16 + r] = f2bf(sigf(og) * tanh_f(cn));
        }
        __syncthreads();   // hsb complete

        // ---- h store (8B/thread) + l1 partial, then ONE drain for both
        {
            unsigned long long pv;
            __builtin_memcpy(&pv, &hsb[hrow][hseg * 4], 8);
            unsigned long long* hdst = (unsigned long long*)(hout
                + (size_t)(m0 + hrow) * H_ + j0 + hseg * 4);
            if (fastf) *hdst = pv;   // plain store: write-through L1 -> shared L2
            else __hip_atomic_store(hdst, pv, __ATOMIC_RELAXED,
                                    __HIP_MEMORY_SCOPE_AGENT);
        }
        {
            const short8 ah = *reinterpret_cast<const short8*>(&hsb[mt_l1 * 16 + r][q * 8]);
            f32x4 d = __builtin_amdgcn_mfma_f32_16x16x32_bf16(
                ah, bl1, (f32x4){0.f, 0.f, 0.f, 0.f}, 0, 0, 0);
            const int f = ft_l1 * 16 + r;
            if (f < HN) {
                float* dst = a1p + ((size_t)t * B_ + m0 + mt_l1 * 16 + q * 4) * A1P + f;
                if (fastf) {
#pragma unroll
                    for (int rr = 0; rr < 4; ++rr) {
                        float* p = dst + rr * A1P;
                        asm volatile("global_atomic_add_f32 %0, %1, off"
                                     :: "v"(p), "v"(d[rr]) : "memory");
                    }
                } else {
#pragma unroll
                    for (int rr = 0; rr < 4; ++rr)
                        __hip_atomic_fetch_add(dst + rr * A1P, d[rr], __ATOMIC_RELAXED,
                                               __HIP_MEMORY_SCOPE_AGENT);
                }
            }
        }
        // drain: h store + l1 atomics acked at L2/IF$ in one round trip
        asm volatile("s_waitcnt vmcnt(0)" ::: "memory");

        // ---- per-wave release: monotonic LDS arrival; 4th wave signals group
        if (t + 1 < T_) {
            if (lane == 0) {
                unsigned old = atomicAdd(&wsig, 1u);
                if (old == (unsigned)(4 * (t + 1) - 1)) {
                    if (fastf) {
                        unsigned one = 1;
                        asm volatile("global_atomic_add %0, %1, off"
                                     :: "v"(ctrB), "v"(one) : "memory");
                    } else {
                        __hip_atomic_fetch_add(ctrA, 1u, __ATOMIC_RELAXED,
                                               __HIP_MEMORY_SCOPE_AGENT);
                    }
                }
            }
            if (!fastf) __syncthreads();   // fallback keeps strict step lockstep
        }
    }
}

// ---------------------------------------------------------------- MLP head
static __device__ __forceinline__ void bn_relu30(float v[HN], const float* __restrict__ gamma,
                                                 const float* __restrict__ beta,
                                                 float (*pS)[HN], float (*pQ)[HN]) {
    float s0[HN], s1[HN];
#pragma unroll
    for (int f = 0; f < HN; ++f) { s0[f] = v[f]; s1[f] = v[f] * v[f]; }
#pragma unroll
    for (int off = 32; off >= 1; off >>= 1) {
#pragma unroll
        for (int f = 0; f < HN; ++f) {
            s0[f] += __shfl_xor(s0[f], off);
            s1[f] += __shfl_xor(s1[f], off);
        }
    }
    const int lane = threadIdx.x & 63, w = threadIdx.x >> 6;
    if (lane == 0) {
#pragma unroll
        for (int f = 0; f < HN; ++f) { pS[w][f] = s0[f]; pQ[w][f] = s1[f]; }
    }
    __syncthreads();
#pragma unroll
    for (int f = 0; f < HN; ++f) {
        float S = 0.f, Q = 0.f;
#pragma unroll
        for (int u = 0; u < 8; ++u) { S += pS[u][f]; Q += pQ[u][f]; }
        float m = S * (1.0f / 512.0f);
        float var = Q * (1.0f / 512.0f) - m * m;     // biased, matches jnp.mean
        float inv = 1.0f / sqrtf(var + EPSf);
        float tv = gamma[f] * (v[f] - m) * inv + beta[f];
        v[f] = fmaxf(tv, 0.f);
    }
    __syncthreads();
}

static __device__ __forceinline__ void layer30(float v[HN], const float* __restrict__ w) {
    float u[HN];
#pragma unroll
    for (int f = 0; f < HN; ++f) {
        float a = 0.f;
#pragma unroll
        for (int k = 0; k < HN; ++k) a = fmaf(v[k], w[f * HN + k], a);
        u[f] = a;
    }
#pragma unroll
    for (int f = 0; f < HN; ++f) v[f] = u[f];
}

__global__ __launch_bounds__(512) void mlp_kernel(
        const float* __restrict__ a1p, const float* __restrict__ l1b,
        const float* __restrict__ l2w, const float* __restrict__ l3w,
        const float* __restrict__ l4w, const float* __restrict__ l5w,
        const float* __restrict__ gamma, const float* __restrict__ beta,
        float* __restrict__ out) {
    const int t = blockIdx.x;
    const int b = threadIdx.x;
    __shared__ float pS[8][HN], pQ[8][HN];
    float v[HN];
    const float* src = a1p + ((size_t)t * B_ + b) * A1P;
#pragma unroll
    for (int f = 0; f < HN; ++f) v[f] = src[f] + l1b[f];
    bn_relu30(v, gamma, beta, pS, pQ);
    layer30(v, l2w); bn_relu30(v, gamma, beta, pS, pQ);
    layer30(v, l3w); bn_relu30(v, gamma, beta, pS, pQ);
    layer30(v, l4w); bn_relu30(v, gamma, beta, pS, pQ);
    float o0 = 0.f, o1 = 0.f;
#pragma unroll
    for (int k = 0; k < HN; ++k) {
        o0 = fmaf(v[k], l5w[k], o0);
        o1 = fmaf(v[k], l5w[HN + k], o1);
    }
    out[(size_t)b * (2 * T_) + t]      = o0;   // out[b][0][t]
    out[(size_t)b * (2 * T_) + T_ + t] = o1;   // out[b][1][t]
}

// ---------------------------------------------------------------- launch
extern "C" void kernel_launch(void* const* d_in, const int* in_sizes, int n_in,
                              void* d_out, int out_size, void* d_ws, size_t ws_size,
                              hipStream_t stream) {
    const float* x    = (const float*)d_in[0];
    const float* Wih  = (const float*)d_in[1];
    const float* Whh  = (const float*)d_in[2];
    const float* bih  = (const float*)d_in[3];
    const float* bhh  = (const float*)d_in[4];
    const float* l1w  = (const float*)d_in[5];
    const float* l1b  = (const float*)d_in[6];
    const float* l2w  = (const float*)d_in[7];
    const float* l3w  = (const float*)d_in[8];
    const float* l4w  = (const float*)d_in[9];
    const float* l5w  = (const float*)d_in[10];
    const float* gam  = (const float*)d_in[11];
    const float* bet  = (const float*)d_in[12];
    float* out = (float*)d_out;

    char* ws = (char*)d_ws;
    unsigned short* Wp   = (unsigned short*)ws;  ws += (size_t)G4 * K_ * 2;            // 2.36 MB
    unsigned short* xb   = (unsigned short*)ws;  ws += (size_t)T_ * B_ * I_ * 2;       // 16.8 MB
    float*          bia  = (float*)ws;           ws += (size_t)G4 * 4;                 // 8 KB
    unsigned short* hb   = (unsigned short*)ws;  ws += (size_t)HROT * B_ * H_ * 2;     // 2 MB
    float*          a1p  = (float*)ws;           ws += (size_t)T_ * B_ * A1P * 4;      // 16.8 MB
    unsigned short* wl1b = (unsigned short*)ws;  ws += (size_t)32 * H_ * 2;            // 32 KB
    unsigned int*   arr  = (unsigned int*)ws;    ws += (size_t)NG * 64 * 4;            // 4 KB
    unsigned int*   map  = (unsigned int*)ws;    ws += (size_t)256 * 4;                // 1 KB

    pack_kernel<<<1024, 256, 0, stream>>>(x, Wih, Whh, bih, bhh, l1w,
                                          Wp, xb, bia, hb, a1p, wl1b, arr, map);
    lstm_kernel<<<NG * GW, 256, 0, stream>>>(Wp, xb, bia, hb, a1p, wl1b, arr, map);
    mlp_kernel<<<T_, 512, 0, stream>>>(a1p, l1b, l2w, l3w, l4w, l5w, gam, bet, out);
}

// Round 14
// 907.350 us; speedup vs baseline: 3471.6264x; 1.5863x over previous
//
#include <hip/hip_runtime.h>
#include <math.h>

#define B_  512
#define T_  256
#define I_  64
#define H_  512
#define G4  2048
#define K_  576   // 512 (h) + 64 (x)
#define HN  30
#define EPSf 1e-5f
#define GW  8     // blocks per group (j-blocks)
#define NG  32    // groups (m-blocks)
#define BM  16
#define BJ  64
#define KP  520   // As pitch in shorts (512 + 8 pad)
#define A1P 32    // a1p padded feature stride
#define HROT 4    // h buffer rotation (L1 eviction + WAR margin)

typedef __attribute__((ext_vector_type(8))) short short8;
typedef __attribute__((ext_vector_type(4))) float f32x4;

static __device__ __forceinline__ unsigned short f2bf(float f) {
    unsigned int u = __float_as_uint(f);
    u += 0x7fffu + ((u >> 16) & 1u);   // round-to-nearest-even
    return (unsigned short)(u >> 16);
}
static __device__ __forceinline__ float sigf(float x) {
    return __builtin_amdgcn_rcpf(1.0f + __expf(-x));
}
static __device__ __forceinline__ float tanh_f(float x) {
    float e = __expf(-2.0f * fabsf(x));
    float r = (1.0f - e) * __builtin_amdgcn_rcpf(1.0f + e);
    return copysignf(r, x);
}

// ---------------------------------------------------------------- pack / init
__global__ void pack_kernel(const float* __restrict__ x, const float* __restrict__ Wih,
                            const float* __restrict__ Whh, const float* __restrict__ bih,
                            const float* __restrict__ bhh, const float* __restrict__ l1w,
                            unsigned short* __restrict__ Wp, unsigned short* __restrict__ xb,
                            float* __restrict__ bias, unsigned short* __restrict__ hb,
                            float* __restrict__ a1p, unsigned short* __restrict__ wl1b,
                            unsigned int* __restrict__ arr, unsigned int* __restrict__ map) {
    const int stride = gridDim.x * blockDim.x;
    const int g0 = blockIdx.x * blockDim.x + threadIdx.x;
    for (int idx = g0; idx < G4 * K_; idx += stride) {
        int n = idx / K_, k = idx - n * K_;
        float v = (k < H_) ? Whh[n * H_ + k] : Wih[n * I_ + (k - H_)];
        Wp[idx] = f2bf(v);
    }
    for (int idx = g0; idx < T_ * B_ * I_; idx += stride) {
        int t = idx / (B_ * I_);
        int r = idx - t * (B_ * I_);
        int b = r / I_, i = r - b * I_;
        xb[idx] = f2bf(x[((size_t)b * T_ + t) * I_ + i]);
    }
    for (int idx = g0; idx < G4; idx += stride) bias[idx] = bih[idx] + bhh[idx];
    for (int idx = g0; idx < B_ * H_; idx += stride) hb[idx] = 0;  // slot 0: h(-1)=0
    for (int idx = g0; idx < T_ * B_ * A1P; idx += stride) a1p[idx] = 0.0f;
    for (int idx = g0; idx < 32 * H_; idx += stride) {
        int f = idx >> 9, k = idx & 511;
        wl1b[idx] = (f < HN) ? f2bf(l1w[f * H_ + k]) : 0;
    }
    for (int idx = g0; idx < NG * 64; idx += stride) arr[idx] = 0u;
    for (int idx = g0; idx < 256; idx += stride) map[idx] = 0u;
}

// ---------------------------------------------------------------- persistent LSTM
// 256 blocks (1/CU) x 256 threads. bid = jb*32 + mb. Group = 8 blocks, same mb
// (16 m-rows, fan-in HALVED vs R11). Wave = j-subtile (16 cols), all 4 gates:
// W = 4g x 18kc = 288 pinned regs/lane (F3). Sync = R11-PROVEN skeleton: tid0
// RMW poll (F1: RMW is the only L1-immune read; few pollers to avoid R13's
// contention) + barrier wake; drain + barrier + tid0 signal; l1 after signal.
// h data: rotation-evicted sc0 loads (F2), plain stores. Agent fallback kept.
__global__ __launch_bounds__(256, 1) void lstm_kernel(
        const unsigned short* __restrict__ Wp, const unsigned short* __restrict__ xb,
        const float* __restrict__ bias, unsigned short* __restrict__ hb,
        float* __restrict__ a1p, const unsigned short* __restrict__ wl1b,
        unsigned int* __restrict__ arr, unsigned int* __restrict__ map) {
    __shared__ unsigned short As[BM][KP];     // A-tile: h only (512 cols), padded
    __shared__ unsigned short hsb[BM][72];    // new h (bf16): store + l1 source
    __shared__ int flagLDS;

    const int tid  = threadIdx.x;
    const int w    = tid >> 6;         // wave = j-subtile 0..3
    const int lane = tid & 63;
    const int r    = lane & 15;        // MFMA: A-row / B-col / D-col
    const int q    = lane >> 4;        // MFMA: k-chunk / D-row group
    const int mb   = blockIdx.x & 31;
    const int jb   = blockIdx.x >> 5;
    const int m0   = mb * BM;
    const int j0   = jb * BJ;
    const int hrow = tid >> 4, hseg = tid & 15;  // staging: lanes 0..15 share row
    const int ft_l1 = w >> 1, kt_l1 = w & 1;     // l1: feature half / k half

    if (tid == 0) {
        unsigned xcc;
        asm volatile("s_getreg_b32 %0, hwreg(HW_REG_XCC_ID)" : "=s"(xcc));
        __hip_atomic_store(&map[blockIdx.x], 0x100u | (xcc & 0xffu),
                           __ATOMIC_RELAXED, __HIP_MEMORY_SCOPE_AGENT);
    }

    // ---- persistent W fragments: 4 gates x 18 k-chunks, cols j0 + w*16 + r
    short8 bfrag[4][18];
#pragma unroll
    for (int g = 0; g < 4; ++g)
#pragma unroll
        for (int kc = 0; kc < 18; ++kc) {
            bfrag[g][kc] = *reinterpret_cast<const short8*>(
                Wp + (size_t)(g * H_ + j0 + w * 16 + r) * K_ + kc * 32 + q * 8);
            asm volatile("" : "+v"(bfrag[g][kc]));
        }
    short8 bl1 = *reinterpret_cast<const short8*>(
        wl1b + (size_t)(ft_l1 * 16 + r) * H_ + j0 + kt_l1 * 32 + q * 8);
    asm volatile("" : "+v"(bl1));

    float bias_g[4];
#pragma unroll
    for (int g = 0; g < 4; ++g) bias_g[g] = bias[g * H_ + j0 + w * 16 + r];

    float c[4] = {0.f, 0.f, 0.f, 0.f};
    unsigned int* ctrA = arr + mb * 64;        // agent-scope counter (IF$ path)
    unsigned int* ctrB = arr + mb * 64 + 32;   // L2-point counter (fast path)
    int fastf = 0;

#pragma unroll 1
    for (int t = 0; t < T_; ++t) {
        const unsigned short* hin = hb + (size_t)(t % HROT) * B_ * H_;
        unsigned short* hout      = hb + (size_t)((t + 1) % HROT) * B_ * H_;

        // ---- wait for h(t-1): tid0 funnel (8 pollers/counter), barrier wake
        if (t > 0) {
            if (tid == 0) {
                if (fastf) {
                    const unsigned target = (unsigned)(GW * (t - 1));
                    unsigned tries = 0;
                    for (;;) {
                        unsigned old, zero = 0;
                        asm volatile("global_atomic_add %0, %1, %2, off sc0\n\t"
                                     "s_waitcnt vmcnt(0)"
                                     : "=&v"(old) : "v"(ctrB), "v"(zero) : "memory");
                        if (old >= target) break;
                        if (++tries > 100000u) break;   // fail loud, never wedge
                        __builtin_amdgcn_s_sleep(1);
                    }
                } else {
                    const unsigned target = (unsigned)(GW * t);
                    unsigned tries = 0;
                    while (__hip_atomic_load(ctrA, __ATOMIC_RELAXED,
                                             __HIP_MEMORY_SCOPE_AGENT) < target) {
                        if (++tries > 100000u) break;
                        __builtin_amdgcn_s_sleep(1);
                    }
                    if (t == 1) {   // group XCD homogeneity check (once)
                        unsigned v0 = __hip_atomic_load(&map[mb], __ATOMIC_RELAXED,
                                                        __HIP_MEMORY_SCOPE_AGENT);
                        int same = (v0 & 0x100u) ? 1 : 0;
                        for (int u = 1; u < GW; ++u) {
                            unsigned vu = __hip_atomic_load(&map[u * 32 + mb],
                                                            __ATOMIC_RELAXED,
                                                            __HIP_MEMORY_SCOPE_AGENT);
                            same &= (vu == v0);
                        }
                        flagLDS = same;
                    }
                }
            }
            __syncthreads();
            if (t == 1) fastf = flagLDS;
            asm volatile("" ::: "memory");
        }

        // ---- x fragments (rows r of this block): direct global->reg
        const unsigned short* xr = xb + ((size_t)t * B_ + m0 + r) * I_ + q * 8;
        const short8 xf0 = *reinterpret_cast<const short8*>(xr);
        const short8 xf1 = *reinterpret_cast<const short8*>(xr + 32);

        // ---- stage A-tile (16 rows x 512): 4 x 16B per thread, lane-contiguous
        short8 hv[4];
        const unsigned short* hbase = hin + (size_t)(m0 + hrow) * H_ + hseg * 8;
        if (fastf) {
#pragma unroll
            for (int u = 0; u < 4; ++u)
                asm volatile("global_load_dwordx4 %0, %1, off sc0"
                             : "=&v"(hv[u]) : "v"(hbase + u * 128));
        } else {
#pragma unroll
            for (int u = 0; u < 4; ++u) {
                unsigned long long p2[2];
                p2[0] = __hip_atomic_load((const unsigned long long*)(hbase + u * 128),
                                          __ATOMIC_RELAXED, __HIP_MEMORY_SCOPE_AGENT);
                p2[1] = __hip_atomic_load((const unsigned long long*)(hbase + u * 128 + 4),
                                          __ATOMIC_RELAXED, __HIP_MEMORY_SCOPE_AGENT);
                __builtin_memcpy(&hv[u], p2, 16);
            }
        }
        asm volatile("s_waitcnt vmcnt(0)" ::: "memory");
        __builtin_amdgcn_sched_barrier(0);
#pragma unroll
        for (int u = 0; u < 4; ++u)
            *reinterpret_cast<short8*>(&As[hrow][u * 128 + hseg * 8]) = hv[u];
        __syncthreads();

        // ---- GEMM: 16 h k-chunks from LDS + 2 x k-chunks from registers
        f32x4 acc[4];
#pragma unroll
        for (int g = 0; g < 4; ++g)
            acc[g] = (f32x4){bias_g[g], bias_g[g], bias_g[g], bias_g[g]};
#pragma unroll
        for (int kc = 0; kc < 16; ++kc) {
            const short8 afr = *reinterpret_cast<const short8*>(
                &As[r][kc * 32 + q * 8]);
#pragma unroll
            for (int g = 0; g < 4; ++g)
                acc[g] = __builtin_amdgcn_mfma_f32_16x16x32_bf16(
                    afr, bfrag[g][kc], acc[g], 0, 0, 0);
        }
#pragma unroll
        for (int g = 0; g < 4; ++g) {
            acc[g] = __builtin_amdgcn_mfma_f32_16x16x32_bf16(xf0, bfrag[g][16], acc[g], 0, 0, 0);
            acc[g] = __builtin_amdgcn_mfma_f32_16x16x32_bf16(xf1, bfrag[g][17], acc[g], 0, 0, 0);
        }

        // ---- cell update: lane-local (D col=r, row=q*4+rr); c in regs
#pragma unroll
        for (int rr = 0; rr < 4; ++rr) {
            float ig = acc[0][rr], fg = acc[1][rr], gg = acc[2][rr], og = acc[3][rr];
            float cn = sigf(fg) * c[rr] + sigf(ig) * tanh_f(gg);
            c[rr] = cn;
            hsb[q * 4 + rr][w * 16 + r] = f2bf(sigf(og) * tanh_f(cn));
        }
        __syncthreads();   // hsb complete

        // ---- h store: one 8B store per thread (16 rows x 16 segs of 8B)
        {
            unsigned long long pv;
            __builtin_memcpy(&pv, &hsb[hrow][hseg * 4], 8);
            unsigned long long* hdst = (unsigned long long*)(hout
                + (size_t)(m0 + hrow) * H_ + j0 + hseg * 4);
            if (fastf) *hdst = pv;   // plain store: write-through L1 -> shared L2
            else __hip_atomic_store(hdst, pv, __ATOMIC_RELAXED,
                                    __HIP_MEMORY_SCOPE_AGENT);
        }

        // ---- release: drain, barrier, tid0 signal (R11-proven ordering)
        if (t + 1 < T_) {
            asm volatile("s_waitcnt vmcnt(0)" ::: "memory");
            __syncthreads();
            if (tid == 0) {
                if (fastf) {
                    unsigned one = 1;
                    asm volatile("global_atomic_add %0, %1, off"
                                 :: "v"(ctrB), "v"(one) : "memory");
                } else {
                    __hip_atomic_fetch_add(ctrA, 1u, __ATOMIC_RELAXED,
                                           __HIP_MEMORY_SCOPE_AGENT);
                }
            }
        } else {
            __syncthreads();
        }

        // ---- l1 partial (overlaps peers' sync): 1 MFMA + 4 atomics
        const short8 ah = *reinterpret_cast<const short8*>(
            &hsb[r][kt_l1 * 32 + q * 8]);
        f32x4 d = __builtin_amdgcn_mfma_f32_16x16x32_bf16(
            ah, bl1, (f32x4){0.f, 0.f, 0.f, 0.f}, 0, 0, 0);
        const int f = ft_l1 * 16 + r;
        if (f < HN) {
            float* dst = a1p + ((size_t)t * B_ + m0 + q * 4) * A1P + f;
            if (fastf) {
#pragma unroll
                for (int rr = 0; rr < 4; ++rr) {
                    float* p = dst + rr * A1P;
                    asm volatile("global_atomic_add_f32 %0, %1, off"
                                 :: "v"(p), "v"(d[rr]) : "memory");
                }
            } else {
#pragma unroll
                for (int rr = 0; rr < 4; ++rr)
                    __hip_atomic_fetch_add(dst + rr * A1P, d[rr], __ATOMIC_RELAXED,
                                           __HIP_MEMORY_SCOPE_AGENT);
            }
        }
    }
}

// ---------------------------------------------------------------- MLP head
static __device__ __forceinline__ void bn_relu30(float v[HN], const float* __restrict__ gamma,
                                                 const float* __restrict__ beta,
                                                 float (*pS)[HN], float (*pQ)[HN]) {
    float s0[HN], s1[HN];
#pragma unroll
    for (int f = 0; f < HN; ++f) { s0[f] = v[f]; s1[f] = v[f] * v[f]; }
#pragma unroll
    for (int off = 32; off >= 1; off >>= 1) {
#pragma unroll
        for (int f = 0; f < HN; ++f) {
            s0[f] += __shfl_xor(s0[f], off);
            s1[f] += __shfl_xor(s1[f], off);
        }
    }
    const int lane = threadIdx.x & 63, w = threadIdx.x >> 6;
    if (lane == 0) {
#pragma unroll
        for (int f = 0; f < HN; ++f) { pS[w][f] = s0[f]; pQ[w][f] = s1[f]; }
    }
    __syncthreads();
#pragma unroll
    for (int f = 0; f < HN; ++f) {
        float S = 0.f, Q = 0.f;
#pragma unroll
        for (int u = 0; u < 8; ++u) { S += pS[u][f]; Q += pQ[u][f]; }
        float m = S * (1.0f / 512.0f);
        float var = Q * (1.0f / 512.0f) - m * m;     // biased, matches jnp.mean
        float inv = 1.0f / sqrtf(var + EPSf);
        float tv = gamma[f] * (v[f] - m) * inv + beta[f];
        v[f] = fmaxf(tv, 0.f);
    }
    __syncthreads();
}

static __device__ __forceinline__ void layer30(float v[HN], const float* __restrict__ w) {
    float u[HN];
#pragma unroll
    for (int f = 0; f < HN; ++f) {
        float a = 0.f;
#pragma unroll
        for (int k = 0; k < HN; ++k) a = fmaf(v[k], w[f * HN + k], a);
        u[f] = a;
    }
#pragma unroll
    for (int f = 0; f < HN; ++f) v[f] = u[f];
}

__global__ __launch_bounds__(512) void mlp_kernel(
        const float* __restrict__ a1p, const float* __restrict__ l1b,
        const float* __restrict__ l2w, const float* __restrict__ l3w,
        const float* __restrict__ l4w, const float* __restrict__ l5w,
        const float* __restrict__ gamma, const float* __restrict__ beta,
        float* __restrict__ out) {
    const int t = blockIdx.x;
    const int b = threadIdx.x;
    __shared__ float pS[8][HN], pQ[8][HN];
    float v[HN];
    const float* src = a1p + ((size_t)t * B_ + b) * A1P;
#pragma unroll
    for (int f = 0; f < HN; ++f) v[f] = src[f] + l1b[f];
    bn_relu30(v, gamma, beta, pS, pQ);
    layer30(v, l2w); bn_relu30(v, gamma, beta, pS, pQ);
    layer30(v, l3w); bn_relu30(v, gamma, beta, pS, pQ);
    layer30(v, l4w); bn_relu30(v, gamma, beta, pS, pQ);
    float o0 = 0.f, o1 = 0.f;
#pragma unroll
    for (int k = 0; k < HN; ++k) {
        o0 = fmaf(v[k], l5w[k], o0);
        o1 = fmaf(v[k], l5w[HN + k], o1);
    }
    out[(size_t)b * (2 * T_) + t]      = o0;   // out[b][0][t]
    out[(size_t)b * (2 * T_) + T_ + t] = o1;   // out[b][1][t]
}

// ---------------------------------------------------------------- launch
extern "C" void kernel_launch(void* const* d_in, const int* in_sizes, int n_in,
                              void* d_out, int out_size, void* d_ws, size_t ws_size,
                              hipStream_t stream) {
    const float* x    = (const float*)d_in[0];
    const float* Wih  = (const float*)d_in[1];
    const float* Whh  = (const float*)d_in[2];
    const float* bih  = (const float*)d_in[3];
    const float* bhh  = (const float*)d_in[4];
    const float* l1w  = (const float*)d_in[5];
    const float* l1b  = (const float*)d_in[6];
    const float* l2w  = (const float*)d_in[7];
    const float* l3w  = (const float*)d_in[8];
    const float* l4w  = (const float*)d_in[9];
    const float* l5w  = (const float*)d_in[10];
    const float* gam  = (const float*)d_in[11];
    const float* bet  = (const float*)d_in[12];
    float* out = (float*)d_out;

    char* ws = (char*)d_ws;
    unsigned short* Wp   = (unsigned short*)ws;  ws += (size_t)G4 * K_ * 2;            // 2.36 MB
    unsigned short* xb   = (unsigned short*)ws;  ws += (size_t)T_ * B_ * I_ * 2;       // 16.8 MB
    float*          bia  = (float*)ws;           ws += (size_t)G4 * 4;                 // 8 KB
    unsigned short* hb   = (unsigned short*)ws;  ws += (size_t)HROT * B_ * H_ * 2;     // 2 MB
    float*          a1p  = (float*)ws;           ws += (size_t)T_ * B_ * A1P * 4;      // 16.8 MB
    unsigned short* wl1b = (unsigned short*)ws;  ws += (size_t)32 * H_ * 2;            // 32 KB
    unsigned int*   arr  = (unsigned int*)ws;    ws += (size_t)NG * 64 * 4;            // 8 KB
    unsigned int*   map  = (unsigned int*)ws;    ws += (size_t)256 * 4;                // 1 KB

    pack_kernel<<<1024, 256, 0, stream>>>(x, Wih, Whh, bih, bhh, l1w,
                                          Wp, xb, bia, hb, a1p, wl1b, arr, map);
    lstm_kernel<<<NG * GW, 256, 0, stream>>>(Wp, xb, bia, hb, a1p, wl1b, arr, map);
    mlp_kernel<<<T_, 512, 0, stream>>>(a1p, l1b, l2w, l3w, l4w, l5w, gam, bet, out);
}